// Round 21
// baseline (2237.900 us; speedup 1.0000x reference)
//
#include <hip/hip_runtime.h>

#define NPTS 2048
#define KNN_K 20
#define BATCH 16

constexpr float EPSV   = 1e-5f;
constexpr float SLOPEV = 0.2f;

__device__ __forceinline__ float dot4(float4 a, float4 b, float acc) {
  acc = fmaf(a.x, b.x, acc);
  acc = fmaf(a.y, b.y, acc);
  acc = fmaf(a.z, b.z, acc);
  acc = fmaf(a.w, b.w, acc);
  return acc;
}

// insert (val, idx) into sorted-desc 20-list, strict > keeps earlier (lower) idx on ties
#define INSERT20(VAL, IDXV)                                              \
  if ((VAL) > topd[KNN_K - 1]) {                                         \
    float d_ = (VAL); int i_ = (IDXV);                                   \
    _Pragma("unroll")                                                    \
    for (int j_ = 0; j_ < KNN_K; ++j_) {                                 \
      bool sw_ = d_ > topd[j_];                                          \
      float td_ = sw_ ? d_ : topd[j_]; float dd_ = sw_ ? topd[j_] : d_;  \
      int   ti_ = sw_ ? i_ : topi[j_]; int  di_ = sw_ ? topi[j_] : i_;   \
      topd[j_] = td_; d_ = dd_; topi[j_] = ti_; i_ = di_;                \
    }                                                                    \
  }

// ---------------- fused pad (C=3 -> C=4) + squared norm ----------------
__global__ void pad_sq_kernel(const float* __restrict__ pc, float* __restrict__ X0P,
                              float* __restrict__ SQ) {
  int i = blockIdx.x * 256 + threadIdx.x;      // point id
  float4 v;
  v.x = pc[i * 3 + 0]; v.y = pc[i * 3 + 1]; v.z = pc[i * 3 + 2]; v.w = 0.f;
  ((float4*)X0P)[i] = v;
  SQ[i] = dot4(v, v, 0.f);
}

// ---------------- squared norms: one thread per (b,n) ----------------
template<int C>
__global__ void sq_kernel(const float* __restrict__ XT, float* __restrict__ SQ) {
  int i = blockIdx.x * 256 + threadIdx.x;      // i = b*NPTS + n
  const float4* r4 = (const float4*)(XT + (long)i * C);
  float s = 0.f;
  #pragma unroll
  for (int c = 0; c < C / 4; ++c) { float4 v = r4[c]; s = dot4(v, v, s); }
  SQ[i] = s;
}

// ---------------- distance GEMM (symmetric): upper-triangle tiles only ------
template<int C>
__global__ __launch_bounds__(256, 2) void dist_kernel(const float* __restrict__ X,   // base [NB][NPTS][C]
                                                      const float* __restrict__ SQc, // base [NB*NPTS]
                                                      float* __restrict__ D) {       // [NB][NPTS][NPTS]
  constexpr int KC = (C % 8 == 0) ? 8 : C;     // 8, or 4 for C=4
  __shared__ float As[KC][132];
  __shared__ float Bs[KC][132];
  __shared__ float Ts[16][132];
  int lin = blockIdx.x;
  int bb = lin / 136;                // batch
  int tid = lin - bb * 136;          // triangular tile id
  int tn = 0, rem = tid;
  while (rem >= 16 - tn) { rem -= 16 - tn; ++tn; }
  int tm = tn + rem;                 // tn <= tm
  int t = threadIdx.x;
  int tx = t & 15, ty = t >> 4;      // tx -> m cols, ty -> n rows
  long base = (long)bb * NPTS;
  const float* Xb = X + base * C;
  int n0 = tn * 128, m0 = tm * 128;

  float acc[8][8];
  #pragma unroll
  for (int i = 0; i < 8; ++i)
    #pragma unroll
    for (int j = 0; j < 8; ++j) acc[i][j] = 0.f;

  for (int k0 = 0; k0 < C; k0 += KC) {
    for (int e = t; e < 32 * KC; e += 256) {
      int row = e / (KC / 4), c4 = e % (KC / 4);
      float4 v = *(const float4*)(Xb + (long)(n0 + row) * C + k0 + c4 * 4);
      As[c4 * 4 + 0][row] = v.x; As[c4 * 4 + 1][row] = v.y;
      As[c4 * 4 + 2][row] = v.z; As[c4 * 4 + 3][row] = v.w;
    }
    for (int e = t; e < 32 * KC; e += 256) {
      int row = e / (KC / 4), c4 = e % (KC / 4);
      float4 v = *(const float4*)(Xb + (long)(m0 + row) * C + k0 + c4 * 4);
      Bs[c4 * 4 + 0][row] = v.x; Bs[c4 * 4 + 1][row] = v.y;
      Bs[c4 * 4 + 2][row] = v.z; Bs[c4 * 4 + 3][row] = v.w;
    }
    __syncthreads();
    #pragma unroll
    for (int k = 0; k < KC; ++k) {
      float4 a0 = *(const float4*)&As[k][ty * 8];
      float4 a1 = *(const float4*)&As[k][ty * 8 + 4];
      float4 b0 = *(const float4*)&Bs[k][tx * 8];
      float4 b1 = *(const float4*)&Bs[k][tx * 8 + 4];
      float av[8] = {a0.x, a0.y, a0.z, a0.w, a1.x, a1.y, a1.z, a1.w};
      float bv[8] = {b0.x, b0.y, b0.z, b0.w, b1.x, b1.y, b1.z, b1.w};
      #pragma unroll
      for (int i = 0; i < 8; ++i)
        #pragma unroll
        for (int j = 0; j < 8; ++j)
          acc[i][j] = fmaf(av[i], bv[j], acc[i][j]);
    }
    __syncthreads();
  }

  float sqn[8], sqm[8];
  #pragma unroll
  for (int i = 0; i < 8; ++i) sqn[i] = SQc[base + n0 + ty * 8 + i];
  #pragma unroll
  for (int j = 0; j < 8; ++j) sqm[j] = SQc[base + m0 + tx * 8 + j];

  #pragma unroll
  for (int i = 0; i < 8; ++i)
    #pragma unroll
    for (int j = 0; j < 8; ++j)
      acc[i][j] = fmaf(2.f, acc[i][j], -sqn[i]) - sqm[j];

  #pragma unroll
  for (int i = 0; i < 8; ++i) {
    float* drow = D + (base + n0 + ty * 8 + i) * NPTS + m0 + tx * 8;
    float4 w0, w1;
    w0.x = acc[i][0]; w0.y = acc[i][1]; w0.z = acc[i][2]; w0.w = acc[i][3];
    w1.x = acc[i][4]; w1.y = acc[i][5]; w1.z = acc[i][6]; w1.w = acc[i][7];
    *(float4*)drow = w0;
    *(float4*)(drow + 4) = w1;
  }

  if (tn != tm) {
    for (int s = 0; s < 8; ++s) {
      if ((tx >> 1) == s) {
        #pragma unroll
        for (int j = 0; j < 8; ++j)
          #pragma unroll
          for (int i = 0; i < 8; ++i)
            Ts[(tx & 1) * 8 + j][ty * 8 + i] = acc[i][j];
      }
      __syncthreads();
      for (int e = t; e < 16 * 32; e += 256) {
        int rr = e >> 5, c4 = e & 31;
        *(float4*)(D + (base + m0 + s * 16 + rr) * NPTS + n0 + c4 * 4) =
            *(const float4*)&Ts[rr][c4 * 4];
      }
      __syncthreads();
    }
  }
}

// ---------------- top-20 select: 8 threads per row, 8-way merge --------------
__global__ __launch_bounds__(256, 2) void select_kernel(const float* __restrict__ D,
                                                        int* __restrict__ IDXc) {
  __shared__ float ld[256][KNN_K];
  __shared__ int   li[256][KNN_K];
  int t = threadIdx.x;
  int rloc = t >> 3, q = t & 7;
  long row = (long)blockIdx.x * 32 + rloc;
  const float4* dr = (const float4*)(D + row * NPTS + q * 256);

  float topd[KNN_K]; int topi[KNN_K];
  #pragma unroll
  for (int j = 0; j < KNN_K; ++j) { topd[j] = -3e38f; topi[j] = 0; }

  int mb = q * 256;
  #pragma unroll 1
  for (int j4 = 0; j4 < 64; j4 += 4) {
    float4 v0 = dr[j4 + 0];
    float4 v1 = dr[j4 + 1];
    float4 v2 = dr[j4 + 2];
    float4 v3 = dr[j4 + 3];
    int m = mb + j4 * 4;
    INSERT20(v0.x, m + 0);
    INSERT20(v0.y, m + 1);
    INSERT20(v0.z, m + 2);
    INSERT20(v0.w, m + 3);
    INSERT20(v1.x, m + 4);
    INSERT20(v1.y, m + 5);
    INSERT20(v1.z, m + 6);
    INSERT20(v1.w, m + 7);
    INSERT20(v2.x, m + 8);
    INSERT20(v2.y, m + 9);
    INSERT20(v2.z, m + 10);
    INSERT20(v2.w, m + 11);
    INSERT20(v3.x, m + 12);
    INSERT20(v3.y, m + 13);
    INSERT20(v3.z, m + 14);
    INSERT20(v3.w, m + 15);
  }

  #pragma unroll
  for (int j = 0; j < KNN_K; ++j) { ld[t][j] = topd[j]; li[t][j] = topi[j]; }
  __syncthreads();

  if (q == 0) {
    int* dst = IDXc + row * KNN_K;
    int ia[8];
    #pragma unroll
    for (int l = 0; l < 8; ++l) ia[l] = 0;
    for (int j = 0; j < KNN_K; ++j) {
      float best = ld[t][ia[0]]; int bl = 0;
      #pragma unroll
      for (int l = 1; l < 8; ++l) {
        float v = ld[t + l][ia[l]];
        if (v > best) { best = v; bl = l; }      // strict > : tie -> lowest l (lowest m)
      }
      dst[j] = li[t + bl][ia[bl]];
      #pragma unroll
      for (int l = 0; l < 8; ++l) ia[l] += (l == bl) ? 1 : 0;
    }
  }
}

// ---------------- edge conv stage 1 (C=3, scalar path) ----------------
template<int O, int C>
__global__ __launch_bounds__(256, 2) void conv_small(const float* __restrict__ XTin,
                                                     const int* __restrict__ IDX,
                                                     const float* __restrict__ W,
                                                     const float* __restrict__ gg,
                                                     const float* __restrict__ bbias,
                                                     const float* __restrict__ mmean,
                                                     const float* __restrict__ vvar,
                                                     float* __restrict__ XTout) {
  constexpr int G   = 256 / O;
  constexpr int KPG = KNN_K / G;
  __shared__ float cols[KNN_K + 1][C];

  int bid = blockIdx.x;               // = b*NPTS + n
  int b = bid >> 11, n = bid & 2047;
  int t = threadIdx.x;
  long rowbase = ((long)b << 11);
  const int* idxp = IDX + (long)bid * KNN_K;

  for (int e = t; e < (KNN_K + 1) * C; e += 256) {
    int col = e / C, c = e - col * C;
    int j = (col == 0) ? n : idxp[col - 1];
    cols[col][c] = XTin[(rowbase + j) * C + c];
  }
  __syncthreads();

  int o = t / G, kg = t - o * G;
  const float* wrow = W + o * (2 * C);

  float acc[KPG];
  #pragma unroll
  for (int q = 0; q < KPG; ++q) acc[q] = 0.f;
  float s1 = 0.f, u2 = 0.f;

  #pragma unroll
  for (int c = 0; c < C; ++c) {
    float w1 = wrow[c];
    float w2 = wrow[C + c];
    float xn = cols[0][c];
    s1 = fmaf(w1, xn, s1);
    u2 = fmaf(w2, xn, u2);
    #pragma unroll
    for (int q = 0; q < KPG; ++q) {
      int k = kg * KPG + q;
      acc[q] = fmaf(w1, cols[1 + k][c], acc[q]);
    }
  }

  float sc = gg[o] / sqrtf(vvar[o] + EPSV);
  float sh = bbias[o] - mmean[o] * sc;
  float vmax = -3e38f;
  #pragma unroll
  for (int q = 0; q < KPG; ++q) {
    float z = acc[q] - s1 + u2;
    float y = fmaf(sc, z, sh);
    y = (y >= 0.f) ? y : SLOPEV * y;
    vmax = fmaxf(vmax, y);
  }
  #pragma unroll
  for (int off = 1; off < G; off <<= 1)
    vmax = fmaxf(vmax, __shfl_xor(vmax, off, 64));
  if (kg == 0) XTout[(rowbase + n) * O + o] = vmax;
}

// ---------------- A/BASE GEMM for stages 2-4 --------------------------------
template<int O, int C>
__global__ __launch_bounds__(256, 2) void ad_kernel(const float* __restrict__ X,
                                                    const float* __restrict__ W,
                                                    float* __restrict__ A,
                                                    float* __restrict__ BASE) {
  static_assert(C % 4 == 0 && 256 % O == 0, "ad shape");
  constexpr int G  = 256 / O;
  constexpr int NP = 16 / G;
  constexpr int C4 = C / 4;
  __shared__ float xs[16][C];

  int blk = blockIdx.x;
  long m0 = (long)blk * 16;
  int t = threadIdx.x;

  for (int e = t; e < 16 * C4; e += 256) {
    int pt = e / C4, c4 = e - pt * C4;
    *(float4*)&xs[pt][c4 * 4] = *(const float4*)(X + (m0 + pt) * C + c4 * 4);
  }
  __syncthreads();

  int o = t % O, pg = t / O;
  const float* wrow = W + o * (2 * C);

  float accA[NP], accD[NP];
  #pragma unroll
  for (int q = 0; q < NP; ++q) { accA[q] = 0.f; accD[q] = 0.f; }

  for (int c4 = 0; c4 < C4; ++c4) {
    float4 w1 = *(const float4*)(wrow + c4 * 4);
    float4 w2 = *(const float4*)(wrow + C + c4 * 4);
    #pragma unroll
    for (int q = 0; q < NP; ++q) {
      float4 xv = *(const float4*)&xs[pg * NP + q][c4 * 4];
      accA[q] = dot4(w1, xv, accA[q]);
      accD[q] = dot4(w2, xv, accD[q]);
    }
  }

  #pragma unroll
  for (int q = 0; q < NP; ++q) {
    long m = m0 + pg * NP + q;
    A[m * O + o]    = accA[q];
    BASE[m * O + o] = accD[q] - accA[q];
  }
}

// ---------------- gather-max: y[p][o] = max_k act(sc*(A[nb_k]+BASE[p])+sh) ---
template<int O>
__global__ __launch_bounds__(256, 4) void gather_kernel(const float* __restrict__ A,
                                                        const int* __restrict__ IDX,
                                                        const float* __restrict__ gg,
                                                        const float* __restrict__ bbias,
                                                        const float* __restrict__ mmean,
                                                        const float* __restrict__ vvar,
                                                        float* __restrict__ XTio) {
  constexpr int PPB = 256 / O;
  int t = threadIdx.x;
  int o = t % O, pp = t / O;
  long p = (long)blockIdx.x * PPB + pp;
  int b = (int)(p >> 11);
  long rowbase = ((long)b << 11);
  const int* idxp = IDX + p * KNN_K;

  float base = XTio[p * O + o];
  float sc = gg[o] / sqrtf(vvar[o] + EPSV);
  float sh = bbias[o] - mmean[o] * sc;

  float vmax = -3e38f;
  #pragma unroll
  for (int k = 0; k < KNN_K; ++k) {
    int nb = idxp[k];
    float a = A[(rowbase + nb) * O + o];
    float y = fmaf(sc, a + base, sh);
    y = (y >= 0.f) ? y : SLOPEV * y;
    vmax = fmaxf(vmax, y);
  }
  XTio[p * O + o] = vmax;
}

// ---------------- final: 4 outputs x 4 points per thread, W5 LDS-staged -----
// k-chunk 8 (was 4): halves the barrier count in the main loop.
// wslab 256x[32+1] = 33KB + tile 33KB = 66.8KB -> still 2 blocks/CU.
__global__ __launch_bounds__(256, 2) void final_kernel(const float* __restrict__ X1,
                                                       const float* __restrict__ X2,
                                                       const float* __restrict__ X3,
                                                       const float* __restrict__ X4,
                                                       const float* __restrict__ W5,
                                                       const float* __restrict__ g5,
                                                       const float* __restrict__ b5,
                                                       const float* __restrict__ m5,
                                                       const float* __restrict__ v5,
                                                       float* __restrict__ RED) {
  __shared__ float tile[16][516];
  __shared__ float wslab[256][33];
  int bid = blockIdx.x;                 // b*128 + chunk
  int b = bid >> 7, chunk = bid & 127;
  int n0 = chunk * 16;
  int t = threadIdx.x;

  for (int e = t; e < 16 * 128; e += 256) {
    int nn = e >> 7, c4 = e & 127;
    int c = c4 * 4;
    long row = ((long)b << 11) + n0 + nn;
    float4 v;
    if      (c < 64)  v = *(const float4*)(X1 + row * 64  + c);
    else if (c < 128) v = *(const float4*)(X2 + row * 64  + (c - 64));
    else if (c < 256) v = *(const float4*)(X3 + row * 128 + (c - 128));
    else              v = *(const float4*)(X4 + row * 256 + (c - 256));
    *(float4*)&tile[nn][c4 * 4] = v;
  }
  __syncthreads();

  int og = t >> 2, pg = t & 3;
  float acc[4][4];
  #pragma unroll
  for (int i = 0; i < 4; ++i)
    #pragma unroll
    for (int j = 0; j < 4; ++j) acc[i][j] = 0.f;

  for (int k0 = 0; k0 < 128; k0 += 8) {   // 16 chunks of 8 c4
    #pragma unroll
    for (int l = 0; l < 8; ++l) {
      int e = t + l * 256;
      int o = e >> 3, part = e & 7;
      *(float4*)&wslab[o][part * 4] = *(const float4*)(W5 + o * 512 + k0 * 4 + part * 4);
    }
    __syncthreads();
    #pragma unroll
    for (int cc = 0; cc < 8; ++cc) {
      float4 w0 = *(const float4*)&wslab[og * 4 + 0][cc * 4];
      float4 w1 = *(const float4*)&wslab[og * 4 + 1][cc * 4];
      float4 w2 = *(const float4*)&wslab[og * 4 + 2][cc * 4];
      float4 w3 = *(const float4*)&wslab[og * 4 + 3][cc * 4];
      float4 x0 = *(const float4*)&tile[pg * 4 + 0][(k0 + cc) * 4];
      float4 x1 = *(const float4*)&tile[pg * 4 + 1][(k0 + cc) * 4];
      float4 x2 = *(const float4*)&tile[pg * 4 + 2][(k0 + cc) * 4];
      float4 x3 = *(const float4*)&tile[pg * 4 + 3][(k0 + cc) * 4];
      acc[0][0] = dot4(w0, x0, acc[0][0]);
      acc[0][1] = dot4(w1, x0, acc[0][1]);
      acc[0][2] = dot4(w2, x0, acc[0][2]);
      acc[0][3] = dot4(w3, x0, acc[0][3]);
      acc[1][0] = dot4(w0, x1, acc[1][0]);
      acc[1][1] = dot4(w1, x1, acc[1][1]);
      acc[1][2] = dot4(w2, x1, acc[1][2]);
      acc[1][3] = dot4(w3, x1, acc[1][3]);
      acc[2][0] = dot4(w0, x2, acc[2][0]);
      acc[2][1] = dot4(w1, x2, acc[2][1]);
      acc[2][2] = dot4(w2, x2, acc[2][2]);
      acc[2][3] = dot4(w3, x2, acc[2][3]);
      acc[3][0] = dot4(w0, x3, acc[3][0]);
      acc[3][1] = dot4(w1, x3, acc[3][1]);
      acc[3][2] = dot4(w2, x3, acc[3][2]);
      acc[3][3] = dot4(w3, x3, acc[3][3]);
    }
    __syncthreads();
  }

  #pragma unroll
  for (int j = 0; j < 4; ++j) {
    int o = og * 4 + j;
    float sc = g5[o] / sqrtf(v5[o] + EPSV);
    float sh = b5[o] - m5[o] * sc;
    float vm = -3e38f;
    #pragma unroll
    for (int i = 0; i < 4; ++i) {
      float y = fmaf(sc, acc[i][j], sh);
      y = (y >= 0.f) ? y : SLOPEV * y;
      vm = fmaxf(vm, y);
    }
    vm = fmaxf(vm, __shfl_xor(vm, 1, 64));
    vm = fmaxf(vm, __shfl_xor(vm, 2, 64));
    if (pg == 0) RED[((long)b * 256 + o) * 128 + chunk] = vm;
  }
}

__global__ void reduce_kernel(const float* __restrict__ RED, float* __restrict__ out) {
  int i = blockIdx.x * 256 + threadIdx.x;
  const float* r = RED + (long)i * 128;
  float v = r[0];
  for (int j = 1; j < 128; ++j) v = fmaxf(v, r[j]);
  out[i] = v;
}

extern "C" void kernel_launch(void* const* d_in, const int* in_sizes, int n_in,
                              void* d_out, int out_size, void* d_ws, size_t ws_size,
                              hipStream_t stream) {
  (void)in_sizes; (void)n_in; (void)out_size;
  const float* pc = (const float*)d_in[0];
  const float* W1 = (const float*)d_in[1];
  const float* g1 = (const float*)d_in[2];
  const float* b1 = (const float*)d_in[3];
  const float* m1 = (const float*)d_in[4];
  const float* v1 = (const float*)d_in[5];
  const float* W2 = (const float*)d_in[6];
  const float* g2 = (const float*)d_in[7];
  const float* b2 = (const float*)d_in[8];
  const float* m2 = (const float*)d_in[9];
  const float* v2 = (const float*)d_in[10];
  const float* W3 = (const float*)d_in[11];
  const float* g3 = (const float*)d_in[12];
  const float* b3 = (const float*)d_in[13];
  const float* m3 = (const float*)d_in[14];
  const float* v3 = (const float*)d_in[15];
  const float* W4 = (const float*)d_in[16];
  const float* g4 = (const float*)d_in[17];
  const float* b4 = (const float*)d_in[18];
  const float* m4 = (const float*)d_in[19];
  const float* v4 = (const float*)d_in[20];
  const float* W5 = (const float*)d_in[21];
  const float* g5 = (const float*)d_in[22];
  const float* b5 = (const float*)d_in[23];
  const float* m5 = (const float*)d_in[24];
  const float* v5 = (const float*)d_in[25];
  float* out = (float*)d_out;

  const int BN = BATCH * NPTS;          // 32768

  // Common prefix (floats): XT1,XT2,XT3,XT4,AD fixed.
  float* XT1 = (float*)d_ws;            // 2097152
  float* XT2 = XT1 + 2097152;           // 2097152
  float* XT3 = XT2 + 2097152;           // 4194304
  float* XT4 = XT3 + 4194304;           // 8388608
  float* AD  = XT4 + 8388608;           // 8388608  (prefix ends at 25165824)

  // Tier ladder: D overlays XT4.. and may extend past AD.
  const size_t NEED16 = 76840960ull * 4ull;
  const size_t NEED8  = 43286528ull * 4ull;
  int nbChunk;                          // batches per knn launch
  if      (ws_size >= NEED16) nbChunk = 16;
  else if (ws_size >= NEED8)  nbChunk = 8;
  else                        nbChunk = 4;

  float* D = XT4;
  long  dFloats = (long)nbChunk * NPTS * NPTS;
  long  tailBase = (dFloats > 16777216L) ? (8388608L + dFloats) : 25165824L;
  float* SQ  = (float*)d_ws + tailBase;   // 32768
  float* RED = SQ + 32768;                // 524288
  int*   IDX = (int*)(RED + 524288);      // 655360 ints
  float* X0P = (float*)(IDX + 655360);    // 131072

  int nKnnLaunch = BATCH / nbChunk;
  int nDistB = nbChunk * 136;
  int nSelB  = nbChunk * (NPTS / 32);
  long CHB   = (long)nbChunk * NPTS;

  // ---- stage 1 (C=3 -> padded C=4) ----
  pad_sq_kernel<<<BN / 256, 256, 0, stream>>>(pc, X0P, SQ);
  for (int ch = 0; ch < nKnnLaunch; ++ch) {
    dist_kernel<4><<<nDistB, 256, 0, stream>>>(X0P + ch * CHB * 4, SQ + ch * CHB, D);
    select_kernel<<<nSelB, 256, 0, stream>>>(D, IDX + ch * CHB * KNN_K);
  }
  conv_small<64, 3><<<BN, 256, 0, stream>>>(pc, IDX, W1, g1, b1, m1, v1, XT1);

  // ---- stage 2 (C=64 -> O=64) ----
  sq_kernel<64><<<BN / 256, 256, 0, stream>>>(XT1, SQ);
  for (int ch = 0; ch < nKnnLaunch; ++ch) {
    dist_kernel<64><<<nDistB, 256, 0, stream>>>(XT1 + ch * CHB * 64, SQ + ch * CHB, D);
    select_kernel<<<nSelB, 256, 0, stream>>>(D, IDX + ch * CHB * KNN_K);
  }
  ad_kernel<64, 64><<<BN / 16, 256, 0, stream>>>(XT1, W2, AD, XT2);
  gather_kernel<64><<<BN / 4, 256, 0, stream>>>(AD, IDX, g2, b2, m2, v2, XT2);

  // ---- stage 3 (C=64 -> O=128) ----
  sq_kernel<64><<<BN / 256, 256, 0, stream>>>(XT2, SQ);
  for (int ch = 0; ch < nKnnLaunch; ++ch) {
    dist_kernel<64><<<nDistB, 256, 0, stream>>>(XT2 + ch * CHB * 64, SQ + ch * CHB, D);
    select_kernel<<<nSelB, 256, 0, stream>>>(D, IDX + ch * CHB * KNN_K);
  }
  ad_kernel<128, 64><<<BN / 16, 256, 0, stream>>>(XT2, W3, AD, XT3);
  gather_kernel<128><<<BN / 2, 256, 0, stream>>>(AD, IDX, g3, b3, m3, v3, XT3);

  // ---- stage 4 (C=128 -> O=256) ----
  sq_kernel<128><<<BN / 256, 256, 0, stream>>>(XT3, SQ);
  for (int ch = 0; ch < nKnnLaunch; ++ch) {
    dist_kernel<128><<<nDistB, 256, 0, stream>>>(XT3 + ch * CHB * 128, SQ + ch * CHB, D);
    select_kernel<<<nSelB, 256, 0, stream>>>(D, IDX + ch * CHB * KNN_K);
  }
  ad_kernel<256, 128><<<BN / 16, 256, 0, stream>>>(XT3, W4, AD, XT4);
  gather_kernel<256><<<BN, 256, 0, stream>>>(AD, IDX, g4, b4, m4, v4, XT4);

  // ---- final ----
  final_kernel<<<BATCH * 128, 256, 0, stream>>>(XT1, XT2, XT3, XT4, W5, g5, b5, m5, v5, RED);
  reduce_kernel<<<BATCH, 256, 0, stream>>>(RED, out);
}

// Round 22
// 2152.176 us; speedup vs baseline: 1.0398x; 1.0398x over previous
//
#include <hip/hip_runtime.h>

#define NPTS 2048
#define KNN_K 20
#define BATCH 16

constexpr float EPSV   = 1e-5f;
constexpr float SLOPEV = 0.2f;

__device__ __forceinline__ float dot4(float4 a, float4 b, float acc) {
  acc = fmaf(a.x, b.x, acc);
  acc = fmaf(a.y, b.y, acc);
  acc = fmaf(a.z, b.z, acc);
  acc = fmaf(a.w, b.w, acc);
  return acc;
}

// insert (val, idx) into sorted-desc 20-list, strict > keeps earlier (lower) idx on ties
#define INSERT20(VAL, IDXV)                                              \
  if ((VAL) > topd[KNN_K - 1]) {                                         \
    float d_ = (VAL); int i_ = (IDXV);                                   \
    _Pragma("unroll")                                                    \
    for (int j_ = 0; j_ < KNN_K; ++j_) {                                 \
      bool sw_ = d_ > topd[j_];                                          \
      float td_ = sw_ ? d_ : topd[j_]; float dd_ = sw_ ? topd[j_] : d_;  \
      int   ti_ = sw_ ? i_ : topi[j_]; int  di_ = sw_ ? topi[j_] : i_;   \
      topd[j_] = td_; d_ = dd_; topi[j_] = ti_; i_ = di_;                \
    }                                                                    \
  }

// ---------------- fused pad (C=3 -> C=4) + squared norm ----------------
__global__ void pad_sq_kernel(const float* __restrict__ pc, float* __restrict__ X0P,
                              float* __restrict__ SQ) {
  int i = blockIdx.x * 256 + threadIdx.x;      // point id
  float4 v;
  v.x = pc[i * 3 + 0]; v.y = pc[i * 3 + 1]; v.z = pc[i * 3 + 2]; v.w = 0.f;
  ((float4*)X0P)[i] = v;
  SQ[i] = dot4(v, v, 0.f);
}

// ---------------- squared norms: one thread per (b,n) ----------------
template<int C>
__global__ void sq_kernel(const float* __restrict__ XT, float* __restrict__ SQ) {
  int i = blockIdx.x * 256 + threadIdx.x;      // i = b*NPTS + n
  const float4* r4 = (const float4*)(XT + (long)i * C);
  float s = 0.f;
  #pragma unroll
  for (int c = 0; c < C / 4; ++c) { float4 v = r4[c]; s = dot4(v, v, s); }
  SQ[i] = s;
}

// ---------------- distance GEMM (symmetric): upper-triangle tiles only ------
template<int C>
__global__ __launch_bounds__(256, 2) void dist_kernel(const float* __restrict__ X,   // base [NB][NPTS][C]
                                                      const float* __restrict__ SQc, // base [NB*NPTS]
                                                      float* __restrict__ D) {       // [NB][NPTS][NPTS]
  constexpr int KC = (C % 8 == 0) ? 8 : C;     // 8, or 4 for C=4
  __shared__ float As[KC][132];
  __shared__ float Bs[KC][132];
  __shared__ float Ts[16][132];
  int lin = blockIdx.x;
  int bb = lin / 136;                // batch
  int tid = lin - bb * 136;          // triangular tile id
  int tn = 0, rem = tid;
  while (rem >= 16 - tn) { rem -= 16 - tn; ++tn; }
  int tm = tn + rem;                 // tn <= tm
  int t = threadIdx.x;
  int tx = t & 15, ty = t >> 4;      // tx -> m cols, ty -> n rows
  long base = (long)bb * NPTS;
  const float* Xb = X + base * C;
  int n0 = tn * 128, m0 = tm * 128;

  float acc[8][8];
  #pragma unroll
  for (int i = 0; i < 8; ++i)
    #pragma unroll
    for (int j = 0; j < 8; ++j) acc[i][j] = 0.f;

  for (int k0 = 0; k0 < C; k0 += KC) {
    for (int e = t; e < 32 * KC; e += 256) {
      int row = e / (KC / 4), c4 = e % (KC / 4);
      float4 v = *(const float4*)(Xb + (long)(n0 + row) * C + k0 + c4 * 4);
      As[c4 * 4 + 0][row] = v.x; As[c4 * 4 + 1][row] = v.y;
      As[c4 * 4 + 2][row] = v.z; As[c4 * 4 + 3][row] = v.w;
    }
    for (int e = t; e < 32 * KC; e += 256) {
      int row = e / (KC / 4), c4 = e % (KC / 4);
      float4 v = *(const float4*)(Xb + (long)(m0 + row) * C + k0 + c4 * 4);
      Bs[c4 * 4 + 0][row] = v.x; Bs[c4 * 4 + 1][row] = v.y;
      Bs[c4 * 4 + 2][row] = v.z; Bs[c4 * 4 + 3][row] = v.w;
    }
    __syncthreads();
    #pragma unroll
    for (int k = 0; k < KC; ++k) {
      float4 a0 = *(const float4*)&As[k][ty * 8];
      float4 a1 = *(const float4*)&As[k][ty * 8 + 4];
      float4 b0 = *(const float4*)&Bs[k][tx * 8];
      float4 b1 = *(const float4*)&Bs[k][tx * 8 + 4];
      float av[8] = {a0.x, a0.y, a0.z, a0.w, a1.x, a1.y, a1.z, a1.w};
      float bv[8] = {b0.x, b0.y, b0.z, b0.w, b1.x, b1.y, b1.z, b1.w};
      #pragma unroll
      for (int i = 0; i < 8; ++i)
        #pragma unroll
        for (int j = 0; j < 8; ++j)
          acc[i][j] = fmaf(av[i], bv[j], acc[i][j]);
    }
    __syncthreads();
  }

  float sqn[8], sqm[8];
  #pragma unroll
  for (int i = 0; i < 8; ++i) sqn[i] = SQc[base + n0 + ty * 8 + i];
  #pragma unroll
  for (int j = 0; j < 8; ++j) sqm[j] = SQc[base + m0 + tx * 8 + j];

  #pragma unroll
  for (int i = 0; i < 8; ++i)
    #pragma unroll
    for (int j = 0; j < 8; ++j)
      acc[i][j] = fmaf(2.f, acc[i][j], -sqn[i]) - sqm[j];

  #pragma unroll
  for (int i = 0; i < 8; ++i) {
    float* drow = D + (base + n0 + ty * 8 + i) * NPTS + m0 + tx * 8;
    float4 w0, w1;
    w0.x = acc[i][0]; w0.y = acc[i][1]; w0.z = acc[i][2]; w0.w = acc[i][3];
    w1.x = acc[i][4]; w1.y = acc[i][5]; w1.z = acc[i][6]; w1.w = acc[i][7];
    *(float4*)drow = w0;
    *(float4*)(drow + 4) = w1;
  }

  if (tn != tm) {
    for (int s = 0; s < 8; ++s) {
      if ((tx >> 1) == s) {
        #pragma unroll
        for (int j = 0; j < 8; ++j)
          #pragma unroll
          for (int i = 0; i < 8; ++i)
            Ts[(tx & 1) * 8 + j][ty * 8 + i] = acc[i][j];
      }
      __syncthreads();
      for (int e = t; e < 16 * 32; e += 256) {
        int rr = e >> 5, c4 = e & 31;
        *(float4*)(D + (base + m0 + s * 16 + rr) * NPTS + n0 + c4 * 4) =
            *(const float4*)&Ts[rr][c4 * 4];
      }
      __syncthreads();
    }
  }
}

// ---------------- top-20 select: 8 threads per row, 8-way merge --------------
__global__ __launch_bounds__(256, 2) void select_kernel(const float* __restrict__ D,
                                                        int* __restrict__ IDXc) {
  __shared__ float ld[256][KNN_K];
  __shared__ int   li[256][KNN_K];
  int t = threadIdx.x;
  int rloc = t >> 3, q = t & 7;
  long row = (long)blockIdx.x * 32 + rloc;
  const float4* dr = (const float4*)(D + row * NPTS + q * 256);

  float topd[KNN_K]; int topi[KNN_K];
  #pragma unroll
  for (int j = 0; j < KNN_K; ++j) { topd[j] = -3e38f; topi[j] = 0; }

  int mb = q * 256;
  #pragma unroll 1
  for (int j4 = 0; j4 < 64; j4 += 4) {
    float4 v0 = dr[j4 + 0];
    float4 v1 = dr[j4 + 1];
    float4 v2 = dr[j4 + 2];
    float4 v3 = dr[j4 + 3];
    int m = mb + j4 * 4;
    INSERT20(v0.x, m + 0);
    INSERT20(v0.y, m + 1);
    INSERT20(v0.z, m + 2);
    INSERT20(v0.w, m + 3);
    INSERT20(v1.x, m + 4);
    INSERT20(v1.y, m + 5);
    INSERT20(v1.z, m + 6);
    INSERT20(v1.w, m + 7);
    INSERT20(v2.x, m + 8);
    INSERT20(v2.y, m + 9);
    INSERT20(v2.z, m + 10);
    INSERT20(v2.w, m + 11);
    INSERT20(v3.x, m + 12);
    INSERT20(v3.y, m + 13);
    INSERT20(v3.z, m + 14);
    INSERT20(v3.w, m + 15);
  }

  #pragma unroll
  for (int j = 0; j < KNN_K; ++j) { ld[t][j] = topd[j]; li[t][j] = topi[j]; }
  __syncthreads();

  if (q == 0) {
    int* dst = IDXc + row * KNN_K;
    int ia[8];
    #pragma unroll
    for (int l = 0; l < 8; ++l) ia[l] = 0;
    for (int j = 0; j < KNN_K; ++j) {
      float best = ld[t][ia[0]]; int bl = 0;
      #pragma unroll
      for (int l = 1; l < 8; ++l) {
        float v = ld[t + l][ia[l]];
        if (v > best) { best = v; bl = l; }      // strict > : tie -> lowest l (lowest m)
      }
      dst[j] = li[t + bl][ia[bl]];
      #pragma unroll
      for (int l = 0; l < 8; ++l) ia[l] += (l == bl) ? 1 : 0;
    }
  }
}

// ---------------- edge conv stage 1 (C=3, scalar path) ----------------
template<int O, int C>
__global__ __launch_bounds__(256, 2) void conv_small(const float* __restrict__ XTin,
                                                     const int* __restrict__ IDX,
                                                     const float* __restrict__ W,
                                                     const float* __restrict__ gg,
                                                     const float* __restrict__ bbias,
                                                     const float* __restrict__ mmean,
                                                     const float* __restrict__ vvar,
                                                     float* __restrict__ XTout) {
  constexpr int G   = 256 / O;
  constexpr int KPG = KNN_K / G;
  __shared__ float cols[KNN_K + 1][C];

  int bid = blockIdx.x;               // = b*NPTS + n
  int b = bid >> 11, n = bid & 2047;
  int t = threadIdx.x;
  long rowbase = ((long)b << 11);
  const int* idxp = IDX + (long)bid * KNN_K;

  for (int e = t; e < (KNN_K + 1) * C; e += 256) {
    int col = e / C, c = e - col * C;
    int j = (col == 0) ? n : idxp[col - 1];
    cols[col][c] = XTin[(rowbase + j) * C + c];
  }
  __syncthreads();

  int o = t / G, kg = t - o * G;
  const float* wrow = W + o * (2 * C);

  float acc[KPG];
  #pragma unroll
  for (int q = 0; q < KPG; ++q) acc[q] = 0.f;
  float s1 = 0.f, u2 = 0.f;

  #pragma unroll
  for (int c = 0; c < C; ++c) {
    float w1 = wrow[c];
    float w2 = wrow[C + c];
    float xn = cols[0][c];
    s1 = fmaf(w1, xn, s1);
    u2 = fmaf(w2, xn, u2);
    #pragma unroll
    for (int q = 0; q < KPG; ++q) {
      int k = kg * KPG + q;
      acc[q] = fmaf(w1, cols[1 + k][c], acc[q]);
    }
  }

  float sc = gg[o] / sqrtf(vvar[o] + EPSV);
  float sh = bbias[o] - mmean[o] * sc;
  float vmax = -3e38f;
  #pragma unroll
  for (int q = 0; q < KPG; ++q) {
    float z = acc[q] - s1 + u2;
    float y = fmaf(sc, z, sh);
    y = (y >= 0.f) ? y : SLOPEV * y;
    vmax = fmaxf(vmax, y);
  }
  #pragma unroll
  for (int off = 1; off < G; off <<= 1)
    vmax = fmaxf(vmax, __shfl_xor(vmax, off, 64));
  if (kg == 0) XTout[(rowbase + n) * O + o] = vmax;
}

// ---------------- A/BASE GEMM for stages 2-4 --------------------------------
template<int O, int C>
__global__ __launch_bounds__(256, 2) void ad_kernel(const float* __restrict__ X,
                                                    const float* __restrict__ W,
                                                    float* __restrict__ A,
                                                    float* __restrict__ BASE) {
  static_assert(C % 4 == 0 && 256 % O == 0, "ad shape");
  constexpr int G  = 256 / O;
  constexpr int NP = 16 / G;
  constexpr int C4 = C / 4;
  __shared__ float xs[16][C];

  int blk = blockIdx.x;
  long m0 = (long)blk * 16;
  int t = threadIdx.x;

  for (int e = t; e < 16 * C4; e += 256) {
    int pt = e / C4, c4 = e - pt * C4;
    *(float4*)&xs[pt][c4 * 4] = *(const float4*)(X + (m0 + pt) * C + c4 * 4);
  }
  __syncthreads();

  int o = t % O, pg = t / O;
  const float* wrow = W + o * (2 * C);

  float accA[NP], accD[NP];
  #pragma unroll
  for (int q = 0; q < NP; ++q) { accA[q] = 0.f; accD[q] = 0.f; }

  for (int c4 = 0; c4 < C4; ++c4) {
    float4 w1 = *(const float4*)(wrow + c4 * 4);
    float4 w2 = *(const float4*)(wrow + C + c4 * 4);
    #pragma unroll
    for (int q = 0; q < NP; ++q) {
      float4 xv = *(const float4*)&xs[pg * NP + q][c4 * 4];
      accA[q] = dot4(w1, xv, accA[q]);
      accD[q] = dot4(w2, xv, accD[q]);
    }
  }

  #pragma unroll
  for (int q = 0; q < NP; ++q) {
    long m = m0 + pg * NP + q;
    A[m * O + o]    = accA[q];
    BASE[m * O + o] = accD[q] - accA[q];
  }
}

// ---------------- gather-max: y[p][o] = max_k act(sc*(A[nb_k]+BASE[p])+sh) ---
template<int O>
__global__ __launch_bounds__(256, 4) void gather_kernel(const float* __restrict__ A,
                                                        const int* __restrict__ IDX,
                                                        const float* __restrict__ gg,
                                                        const float* __restrict__ bbias,
                                                        const float* __restrict__ mmean,
                                                        const float* __restrict__ vvar,
                                                        float* __restrict__ XTio) {
  constexpr int PPB = 256 / O;
  int t = threadIdx.x;
  int o = t % O, pp = t / O;
  long p = (long)blockIdx.x * PPB + pp;
  int b = (int)(p >> 11);
  long rowbase = ((long)b << 11);
  const int* idxp = IDX + p * KNN_K;

  float base = XTio[p * O + o];
  float sc = gg[o] / sqrtf(vvar[o] + EPSV);
  float sh = bbias[o] - mmean[o] * sc;

  float vmax = -3e38f;
  #pragma unroll
  for (int k = 0; k < KNN_K; ++k) {
    int nb = idxp[k];
    float a = A[(rowbase + nb) * O + o];
    float y = fmaf(sc, a + base, sh);
    y = (y >= 0.f) ? y : SLOPEV * y;
    vmax = fmaxf(vmax, y);
  }
  XTio[p * O + o] = vmax;
}

// ---------------- final: 4 outputs x 4 points per thread, W5 LDS-staged -----
__global__ __launch_bounds__(256, 2) void final_kernel(const float* __restrict__ X1,
                                                       const float* __restrict__ X2,
                                                       const float* __restrict__ X3,
                                                       const float* __restrict__ X4,
                                                       const float* __restrict__ W5,
                                                       const float* __restrict__ g5,
                                                       const float* __restrict__ b5,
                                                       const float* __restrict__ m5,
                                                       const float* __restrict__ v5,
                                                       float* __restrict__ RED) {
  __shared__ float tile[16][516];
  __shared__ float wslab[256][17];
  int bid = blockIdx.x;                 // b*128 + chunk
  int b = bid >> 7, chunk = bid & 127;
  int n0 = chunk * 16;
  int t = threadIdx.x;

  for (int e = t; e < 16 * 128; e += 256) {
    int nn = e >> 7, c4 = e & 127;
    int c = c4 * 4;
    long row = ((long)b << 11) + n0 + nn;
    float4 v;
    if      (c < 64)  v = *(const float4*)(X1 + row * 64  + c);
    else if (c < 128) v = *(const float4*)(X2 + row * 64  + (c - 64));
    else if (c < 256) v = *(const float4*)(X3 + row * 128 + (c - 128));
    else              v = *(const float4*)(X4 + row * 256 + (c - 256));
    *(float4*)&tile[nn][c4 * 4] = v;
  }
  __syncthreads();

  int og = t >> 2, pg = t & 3;
  float acc[4][4];
  #pragma unroll
  for (int i = 0; i < 4; ++i)
    #pragma unroll
    for (int j = 0; j < 4; ++j) acc[i][j] = 0.f;

  for (int k0 = 0; k0 < 128; k0 += 4) {   // 32 chunks of 4 c4
    #pragma unroll
    for (int l = 0; l < 4; ++l) {
      int e = t + l * 256;
      int o = e >> 2, part = e & 3;
      *(float4*)&wslab[o][part * 4] = *(const float4*)(W5 + o * 512 + k0 * 4 + part * 4);
    }
    __syncthreads();
    #pragma unroll
    for (int cc = 0; cc < 4; ++cc) {
      float4 w0 = *(const float4*)&wslab[og * 4 + 0][cc * 4];
      float4 w1 = *(const float4*)&wslab[og * 4 + 1][cc * 4];
      float4 w2 = *(const float4*)&wslab[og * 4 + 2][cc * 4];
      float4 w3 = *(const float4*)&wslab[og * 4 + 3][cc * 4];
      float4 x0 = *(const float4*)&tile[pg * 4 + 0][(k0 + cc) * 4];
      float4 x1 = *(const float4*)&tile[pg * 4 + 1][(k0 + cc) * 4];
      float4 x2 = *(const float4*)&tile[pg * 4 + 2][(k0 + cc) * 4];
      float4 x3 = *(const float4*)&tile[pg * 4 + 3][(k0 + cc) * 4];
      acc[0][0] = dot4(w0, x0, acc[0][0]);
      acc[0][1] = dot4(w1, x0, acc[0][1]);
      acc[0][2] = dot4(w2, x0, acc[0][2]);
      acc[0][3] = dot4(w3, x0, acc[0][3]);
      acc[1][0] = dot4(w0, x1, acc[1][0]);
      acc[1][1] = dot4(w1, x1, acc[1][1]);
      acc[1][2] = dot4(w2, x1, acc[1][2]);
      acc[1][3] = dot4(w3, x1, acc[1][3]);
      acc[2][0] = dot4(w0, x2, acc[2][0]);
      acc[2][1] = dot4(w1, x2, acc[2][1]);
      acc[2][2] = dot4(w2, x2, acc[2][2]);
      acc[2][3] = dot4(w3, x2, acc[2][3]);
      acc[3][0] = dot4(w0, x3, acc[3][0]);
      acc[3][1] = dot4(w1, x3, acc[3][1]);
      acc[3][2] = dot4(w2, x3, acc[3][2]);
      acc[3][3] = dot4(w3, x3, acc[3][3]);
    }
    __syncthreads();
  }

  #pragma unroll
  for (int j = 0; j < 4; ++j) {
    int o = og * 4 + j;
    float sc = g5[o] / sqrtf(v5[o] + EPSV);
    float sh = b5[o] - m5[o] * sc;
    float vm = -3e38f;
    #pragma unroll
    for (int i = 0; i < 4; ++i) {
      float y = fmaf(sc, acc[i][j], sh);
      y = (y >= 0.f) ? y : SLOPEV * y;
      vm = fmaxf(vm, y);
    }
    vm = fmaxf(vm, __shfl_xor(vm, 1, 64));
    vm = fmaxf(vm, __shfl_xor(vm, 2, 64));
    if (pg == 0) RED[((long)b * 256 + o) * 128 + chunk] = vm;
  }
}

__global__ void reduce_kernel(const float* __restrict__ RED, float* __restrict__ out) {
  int i = blockIdx.x * 256 + threadIdx.x;
  const float* r = RED + (long)i * 128;
  float v = r[0];
  for (int j = 1; j < 128; ++j) v = fmaxf(v, r[j]);
  out[i] = v;
}

extern "C" void kernel_launch(void* const* d_in, const int* in_sizes, int n_in,
                              void* d_out, int out_size, void* d_ws, size_t ws_size,
                              hipStream_t stream) {
  (void)in_sizes; (void)n_in; (void)out_size;
  const float* pc = (const float*)d_in[0];
  const float* W1 = (const float*)d_in[1];
  const float* g1 = (const float*)d_in[2];
  const float* b1 = (const float*)d_in[3];
  const float* m1 = (const float*)d_in[4];
  const float* v1 = (const float*)d_in[5];
  const float* W2 = (const float*)d_in[6];
  const float* g2 = (const float*)d_in[7];
  const float* b2 = (const float*)d_in[8];
  const float* m2 = (const float*)d_in[9];
  const float* v2 = (const float*)d_in[10];
  const float* W3 = (const float*)d_in[11];
  const float* g3 = (const float*)d_in[12];
  const float* b3 = (const float*)d_in[13];
  const float* m3 = (const float*)d_in[14];
  const float* v3 = (const float*)d_in[15];
  const float* W4 = (const float*)d_in[16];
  const float* g4 = (const float*)d_in[17];
  const float* b4 = (const float*)d_in[18];
  const float* m4 = (const float*)d_in[19];
  const float* v4 = (const float*)d_in[20];
  const float* W5 = (const float*)d_in[21];
  const float* g5 = (const float*)d_in[22];
  const float* b5 = (const float*)d_in[23];
  const float* m5 = (const float*)d_in[24];
  const float* v5 = (const float*)d_in[25];
  float* out = (float*)d_out;

  const int BN = BATCH * NPTS;          // 32768

  // Common prefix (floats): XT1,XT2,XT3,XT4,AD fixed.
  float* XT1 = (float*)d_ws;            // 2097152
  float* XT2 = XT1 + 2097152;           // 2097152
  float* XT3 = XT2 + 2097152;           // 4194304
  float* XT4 = XT3 + 4194304;           // 8388608
  float* AD  = XT4 + 8388608;           // 8388608  (prefix ends at 25165824)

  // Tier ladder: D overlays XT4.. and may extend past AD.
  const size_t NEED16 = 76840960ull * 4ull;
  const size_t NEED8  = 43286528ull * 4ull;
  int nbChunk;                          // batches per knn launch
  if      (ws_size >= NEED16) nbChunk = 16;
  else if (ws_size >= NEED8)  nbChunk = 8;
  else                        nbChunk = 4;

  float* D = XT4;
  long  dFloats = (long)nbChunk * NPTS * NPTS;
  long  tailBase = (dFloats > 16777216L) ? (8388608L + dFloats) : 25165824L;
  float* SQ  = (float*)d_ws + tailBase;   // 32768
  float* RED = SQ + 32768;                // 524288
  int*   IDX = (int*)(RED + 524288);      // 655360 ints
  float* X0P = (float*)(IDX + 655360);    // 131072

  int nKnnLaunch = BATCH / nbChunk;
  int nDistB = nbChunk * 136;
  int nSelB  = nbChunk * (NPTS / 32);
  long CHB   = (long)nbChunk * NPTS;

  // ---- stage 1 (C=3 -> padded C=4) ----
  pad_sq_kernel<<<BN / 256, 256, 0, stream>>>(pc, X0P, SQ);
  for (int ch = 0; ch < nKnnLaunch; ++ch) {
    dist_kernel<4><<<nDistB, 256, 0, stream>>>(X0P + ch * CHB * 4, SQ + ch * CHB, D);
    select_kernel<<<nSelB, 256, 0, stream>>>(D, IDX + ch * CHB * KNN_K);
  }
  conv_small<64, 3><<<BN, 256, 0, stream>>>(pc, IDX, W1, g1, b1, m1, v1, XT1);

  // ---- stage 2 (C=64 -> O=64) ----
  sq_kernel<64><<<BN / 256, 256, 0, stream>>>(XT1, SQ);
  for (int ch = 0; ch < nKnnLaunch; ++ch) {
    dist_kernel<64><<<nDistB, 256, 0, stream>>>(XT1 + ch * CHB * 64, SQ + ch * CHB, D);
    select_kernel<<<nSelB, 256, 0, stream>>>(D, IDX + ch * CHB * KNN_K);
  }
  ad_kernel<64, 64><<<BN / 16, 256, 0, stream>>>(XT1, W2, AD, XT2);
  gather_kernel<64><<<BN / 4, 256, 0, stream>>>(AD, IDX, g2, b2, m2, v2, XT2);

  // ---- stage 3 (C=64 -> O=128) ----
  sq_kernel<64><<<BN / 256, 256, 0, stream>>>(XT2, SQ);
  for (int ch = 0; ch < nKnnLaunch; ++ch) {
    dist_kernel<64><<<nDistB, 256, 0, stream>>>(XT2 + ch * CHB * 64, SQ + ch * CHB, D);
    select_kernel<<<nSelB, 256, 0, stream>>>(D, IDX + ch * CHB * KNN_K);
  }
  ad_kernel<128, 64><<<BN / 16, 256, 0, stream>>>(XT2, W3, AD, XT3);
  gather_kernel<128><<<BN / 2, 256, 0, stream>>>(AD, IDX, g3, b3, m3, v3, XT3);

  // ---- stage 4 (C=128 -> O=256) ----
  sq_kernel<128><<<BN / 256, 256, 0, stream>>>(XT3, SQ);
  for (int ch = 0; ch < nKnnLaunch; ++ch) {
    dist_kernel<128><<<nDistB, 256, 0, stream>>>(XT3 + ch * CHB * 128, SQ + ch * CHB, D);
    select_kernel<<<nSelB, 256, 0, stream>>>(D, IDX + ch * CHB * KNN_K);
  }
  ad_kernel<256, 128><<<BN / 16, 256, 0, stream>>>(XT3, W4, AD, XT4);
  gather_kernel<256><<<BN, 256, 0, stream>>>(AD, IDX, g4, b4, m4, v4, XT4);

  // ---- final ----
  final_kernel<<<BATCH * 128, 256, 0, stream>>>(XT1, XT2, XT3, XT4, W5, g5, b5, m5, v5, RED);
  reduce_kernel<<<BATCH, 256, 0, stream>>>(RED, out);
}